// Round 1
// 190.474 us; speedup vs baseline: 1.0140x; 1.0140x over previous
//
#include <hip/hip_runtime.h>

#define TT 2048
#define BB 2
#define EE 1024
#define HH 16
#define DD 64
#define E3 3072
#define NTOK 4096

typedef unsigned short u16;
typedef _Float16 __attribute__((ext_vector_type(8))) half8;
typedef __fp16 __attribute__((ext_vector_type(2))) fp16x2;
typedef __attribute__((ext_vector_type(4))) float f32x4;

__device__ __forceinline__ unsigned f2h(float f) {
    union { _Float16 h; u16 u; } v; v.h = (_Float16)f; return (unsigned)v.u;
}
// packed f32x2 -> f16x2 (round-toward-zero), one VALU op
__device__ __forceinline__ unsigned pkh(float a, float b) {
    union { fp16x2 h; unsigned u; } v;
    v.h = __builtin_amdgcn_cvt_pkrtz(a, b);
    return v.u;
}

// async global->LDS, 16 B per lane; lds ptr must be wave-uniform
__device__ __forceinline__ void async_ld16(const u16* g, const u16* l) {
    auto gp = reinterpret_cast<const __attribute__((address_space(1))) unsigned*>(
        reinterpret_cast<uintptr_t>(g));
    auto lp = reinterpret_cast<__attribute__((address_space(3))) unsigned*>(
        reinterpret_cast<uintptr_t>(l));
    __builtin_amdgcn_global_load_lds(gp, lp, 16, 0, 0);
}

// fp32 -> f16 convert for x, qkv_w, out_w in ONE launch.
__global__ __launch_bounds__(256) void split3(
    const float* __restrict__ x, const float* __restrict__ w1,
    const float* __restrict__ w2,
    u16* __restrict__ xh, u16* __restrict__ w1h, u16* __restrict__ w2h)
{
    const int N1 = (NTOK * EE) / 4;
    const int N2 = N1 + (E3 * EE) / 4;
    int i = blockIdx.x * 256 + threadIdx.x;
    const float* src; u16* dst; int j;
    if (i < N1)      { src = x;  dst = xh;  j = i; }
    else if (i < N2) { src = w1; dst = w1h; j = i - N1; }
    else             { src = w2; dst = w2h; j = i - N2; }
    float4 v = ((const float4*)src)[j];
    *(uint2*)&dst[(size_t)j * 4] = make_uint2(
        f2h(v.x) | (f2h(v.y) << 16), f2h(v.z) | (f2h(v.w) << 16));
}

// One-shot V transpose: qkv[b][t][2E + h*64 + d] -> vt[b][h][d][t]  (f16 bits)
__global__ __launch_bounds__(256) void vtrans(
    const u16* __restrict__ qkv, u16* __restrict__ vt)
{
    __shared__ u16 L[64][72];
    const int tid = threadIdx.x;
    const int t0 = blockIdx.x * 64;
    const int h  = blockIdx.y;
    const int b  = blockIdx.z;
    const int row = tid >> 2;
    const int c16 = (tid & 3) << 4;

    const u16* src = qkv + (size_t)(b * TT + t0 + row) * E3 + 2 * EE + h * DD + c16;
    *(uint4*)&L[row][c16]     = *(const uint4*)src;
    *(uint4*)&L[row][c16 + 8] = *(const uint4*)(src + 8);
    __syncthreads();

    union { uint4 u[2]; u16 s[16]; } P;
#pragma unroll
    for (int j = 0; j < 16; ++j) P.s[j] = L[c16 + j][row];
    u16* dst = vt + ((size_t)(b * HH + h) * DD + row) * TT + t0 + c16;
    *(uint4*)dst       = P.u[0];
    *(uint4*)(dst + 8) = P.u[1];
}

// f16 MFMA GEMM, BK=64 (half the barriers of BK=32):
// C[M,N] = A[M,1024] @ W[N,1024]^T + bias.  QSCALE: q-third (n0<EE) of the
// output is multiplied by 0.125*log2(e) so attention can use exp2 directly.
// LDS rows [row][64], phys chunk = chunk ^ (row&7): linear glds dest,
// 2-way b128 frag reads (free).
template <int WMT, bool QSCALE, bool F16OUT>
__global__ __launch_bounds__(256, 3) void gemm_f16(
    const u16* __restrict__ Ag, const u16* __restrict__ Wg,
    const float* __restrict__ bias, void* __restrict__ Cout, int M, int N)
{
    constexpr int BM = WMT * 32;
    constexpr int APASS = BM / 32;
    __shared__ u16 sA[BM * 64];
    __shared__ u16 sB[128 * 64];

    const int tid  = threadIdx.x;
    const int lane = tid & 63;
    const int wave = tid >> 6;
    const int quad = lane >> 4;
    const int l16  = lane & 15;
    const int wm = wave >> 1, wn = wave & 1;
    const int m0 = blockIdx.y * BM;
    const int n0 = blockIdx.x * 128;

    const int srow = tid >> 3;      // staging row (+32/pass)
    const int schk = tid & 7;       // 16B chunk

    const u16* ag[APASS]; int aldw[APASS];
#pragma unroll
    for (int p = 0; p < APASS; ++p) {
        int row = p * 32 + srow;
        ag[p] = Ag + (size_t)(m0 + row) * EE + ((schk ^ (row & 7)) << 3);
        aldw[p] = (p * 256 + wave * 64) * 8;
    }
    const u16* bg[4]; int bldw[4];
#pragma unroll
    for (int p = 0; p < 4; ++p) {
        int row = p * 32 + srow;
        bg[p] = Wg + (size_t)(n0 + row) * EE + ((schk ^ (row & 7)) << 3);
        bldw[p] = (p * 256 + wave * 64) * 8;
    }

    f32x4 acc[WMT][4];
#pragma unroll
    for (int mt = 0; mt < WMT; ++mt)
#pragma unroll
        for (int nt = 0; nt < 4; ++nt) acc[mt][nt] = (f32x4){0.f, 0.f, 0.f, 0.f};

    for (int k0 = 0; k0 < EE; k0 += 64) {
        __syncthreads();
#pragma unroll
        for (int p = 0; p < APASS; ++p) async_ld16(ag[p] + k0, sA + aldw[p]);
#pragma unroll
        for (int p = 0; p < 4; ++p)    async_ld16(bg[p] + k0, sB + bldw[p]);
        __syncthreads();

        half8 fa[WMT][2], fb[4][2];
#pragma unroll
        for (int mt = 0; mt < WMT; ++mt) {
            int r = wm * (WMT * 16) + mt * 16 + l16;
#pragma unroll
            for (int ks = 0; ks < 2; ++ks)
                fa[mt][ks] = *(const half8*)&sA[r * 64 + (((ks * 4 + quad) ^ (r & 7)) << 3)];
        }
#pragma unroll
        for (int nt = 0; nt < 4; ++nt) {
            int r = wn * 64 + nt * 16 + l16;
#pragma unroll
            for (int ks = 0; ks < 2; ++ks)
                fb[nt][ks] = *(const half8*)&sB[r * 64 + (((ks * 4 + quad) ^ (r & 7)) << 3)];
        }
#pragma unroll
        for (int ks = 0; ks < 2; ++ks)
#pragma unroll
            for (int mt = 0; mt < WMT; ++mt)
#pragma unroll
                for (int nt = 0; nt < 4; ++nt)
                    acc[mt][nt] = __builtin_amdgcn_mfma_f32_16x16x32_f16(
                        fa[mt][ks], fb[nt][ks], acc[mt][nt], 0, 0, 0);
    }

    const float scale = (QSCALE && n0 < EE) ? 0.18033688011112042f : 1.0f;
    float bv[4];
#pragma unroll
    for (int nt = 0; nt < 4; ++nt) bv[nt] = bias[n0 + wn * 64 + nt * 16 + l16];
#pragma unroll
    for (int mt = 0; mt < WMT; ++mt)
#pragma unroll
        for (int nt = 0; nt < 4; ++nt)
#pragma unroll
            for (int r = 0; r < 4; ++r) {
                int rg = m0 + wm * (WMT * 16) + mt * 16 + quad * 4 + r;
                int cg = n0 + wn * 64 + nt * 16 + l16;
                float v = (acc[mt][nt][r] + bv[nt]) * scale;
                if (F16OUT) ((u16*)Cout)[(size_t)rg * N + cg] = (u16)f2h(v);
                else        ((float*)Cout)[(size_t)rg * N + cg] = v;
            }
}

// S^T/O^T f16 MFMA flash attention, 16 q/wave (64 q/block), no-max softmax
// (q pre-scaled by 0.125*log2e in gemm1 epilogue -> raw exp2), dbuf K/V glds
// prefetch, one barrier/iter.
// Q-tile 64 => grid 1024 blocks, LDS 40 KB => 4 blocks/CU (was 2): the
// kernel is latency-bound (MfmaUtil 25 / VALUBusy 32 / Occ 17), and the
// serial exp2->pack->P-read chain between the two MFMA clusters can only be
// hidden by waves from OTHER blocks at different pipeline phases.
__global__ __launch_bounds__(256, 4) void attn_mfma(
    const u16* __restrict__ qkv, const u16* __restrict__ vt,
    u16* __restrict__ obuf)
{
    __shared__ u16 KB[2][64][64];   // [buf][key][d chunks swz]
    __shared__ u16 VB[2][64][64];   // [buf][d][key chunks swz]
    __shared__ u16 QP[64][64];      // Q staging, then P [q_loc][key]

    const int tid  = threadIdx.x;
    const int wave = tid >> 6;
    const int lane = tid & 63;
    const int quad = lane >> 4;
    const int l16  = lane & 15;

    const int q0 = blockIdx.x * 64;
    const int hh = blockIdx.y;
    const int b  = blockIdx.z;

    const int srow = tid >> 3;
    const int schk = tid & 7;
    const int ldsw = wave * 512;

    // ---- prologue: stage Q (2 passes), K/V tile 0 (2 passes each) ----
#pragma unroll
    for (int p = 0; p < 2; ++p) {
        int row = p * 32 + srow;
        const u16* qg = qkv + (size_t)(b * TT + q0 + row) * E3 + hh * DD
                        + ((schk ^ (row & 7)) << 3);
        async_ld16(qg, &QP[0][0] + p * 2048 + ldsw);
    }
#pragma unroll
    for (int p = 0; p < 2; ++p) {
        int row = p * 32 + srow;
        int sw8 = (schk ^ (row & 7)) << 3;
        async_ld16(qkv + (size_t)(b * TT + row) * E3 + EE + hh * DD + sw8,
                   &KB[0][0][0] + p * 2048 + ldsw);
        async_ld16(vt + ((size_t)(b * HH + hh) * DD + row) * TT + sw8,
                   &VB[0][0][0] + p * 2048 + ldsw);
    }
    __syncthreads();

    // Q fragments -> registers (loop-invariant); QP rows [wave*16,+16) are
    // wave-private afterwards (P overwrites them, in-wave DS order is safe)
    half8 qb[2];
    {
        int row = wave * 16 + l16;
#pragma unroll
        for (int ks = 0; ks < 2; ++ks)
            qb[ks] = *(const half8*)&QP[row][((ks * 4 + quad) ^ (row & 7)) << 3];
    }

    const f32x4 Z = {0.f, 0.f, 0.f, 0.f};   // loop-invariant zero C operand
    float l_i = 0.f;
    f32x4 o[4];
#pragma unroll
    for (int dt = 0; dt < 4; ++dt) o[dt] = (f32x4){0.f, 0.f, 0.f, 0.f};

    int cur = 0;
    for (int kt = 0; kt < TT; kt += 64, cur ^= 1) {
        // ---- prefetch next K/V tile into alternate buffer ----
        const int ktn = (kt + 64) & (TT - 1);
#pragma unroll
        for (int p = 0; p < 2; ++p) {
            int row = p * 32 + srow;
            int sw8 = (schk ^ (row & 7)) << 3;
            async_ld16(qkv + (size_t)(b * TT + ktn + row) * E3 + EE + hh * DD + sw8,
                       &KB[cur ^ 1][0][0] + p * 2048 + ldsw);
            async_ld16(vt + ((size_t)(b * HH + hh) * DD + row) * TT + ktn + sw8,
                       &VB[cur ^ 1][0][0] + p * 2048 + ldsw);
        }

        // ---- S^T = K * Q^T : 64 keys x 16 q per wave ----
        f32x4 s[4];
#pragma unroll
        for (int nt = 0; nt < 4; ++nt) {
            int r0 = nt * 16 + l16;
            half8 kf0 = *(const half8*)&KB[cur][r0][((quad)     ^ (r0 & 7)) << 3];
            half8 kf1 = *(const half8*)&KB[cur][r0][((4 + quad) ^ (r0 & 7)) << 3];
            f32x4 t = __builtin_amdgcn_mfma_f32_16x16x32_f16(kf0, qb[0], Z, 0, 0, 0);
            s[nt] = __builtin_amdgcn_mfma_f32_16x16x32_f16(kf1, qb[1], t, 0, 0, 0);
        }

        // ---- exp2 (q pre-scaled), pack P via cvt_pkrtz into wave-private QP ----
        {
            int prow = wave * 16 + l16;
            float rs0 = 0.f, rs1 = 0.f;
#pragma unroll
            for (int nt = 0; nt < 4; ++nt) {
                float p0 = __builtin_amdgcn_exp2f(s[nt][0]);
                float p1 = __builtin_amdgcn_exp2f(s[nt][1]);
                float p2 = __builtin_amdgcn_exp2f(s[nt][2]);
                float p3 = __builtin_amdgcn_exp2f(s[nt][3]);
                rs0 += p0 + p1;
                rs1 += p2 + p3;
                int phys = (nt * 2 + (quad >> 1)) ^ (prow & 7);
                *(uint2*)&QP[prow][phys * 8 + ((quad & 1) << 2)] =
                    make_uint2(pkh(p0, p1), pkh(p2, p3));
            }
            l_i += rs0 + rs1;
        }

        // ---- O^T += V^T * P^T ----
#pragma unroll
        for (int ks = 0; ks < 2; ++ks) {
            int prow = wave * 16 + l16;
            half8 pf = *(const half8*)&QP[prow][((ks * 4 + quad) ^ (prow & 7)) << 3];
#pragma unroll
            for (int dt = 0; dt < 4; ++dt) {
                int vr = dt * 16 + l16;
                half8 vf = *(const half8*)&VB[cur][vr][((ks * 4 + quad) ^ (vr & 7)) << 3];
                o[dt] = __builtin_amdgcn_mfma_f32_16x16x32_f16(vf, pf, o[dt], 0, 0, 0);
            }
        }

        __syncthreads();   // publishes prefetch + closes buffer swap
    }

    // ---- epilogue: reduce l over quad-groups, normalize, store f16 (RTNE) ----
    float inv;
    {
        float l = l_i;
        l += __shfl_xor(l, 16, 64);
        l += __shfl_xor(l, 32, 64);
        inv = 1.f / l;
    }
    {
        size_t base = (size_t)(b * TT + q0 + wave * 16 + l16) * EE + hh * DD;
#pragma unroll
        for (int dt = 0; dt < 4; ++dt) {
            unsigned hv[4];
#pragma unroll
            for (int r = 0; r < 4; ++r) hv[r] = f2h(o[dt][r] * inv);
            *(uint2*)&obuf[base + dt * 16 + quad * 4] =
                make_uint2(hv[0] | (hv[1] << 16), hv[2] | (hv[3] << 16));
        }
    }
}

extern "C" void kernel_launch(void* const* d_in, const int* in_sizes, int n_in,
                              void* d_out, int out_size, void* d_ws, size_t ws_size,
                              hipStream_t stream)
{
    const float* x     = (const float*)d_in[0];
    const float* qkv_w = (const float*)d_in[1];
    const float* qkv_b = (const float*)d_in[2];
    const float* out_w = (const float*)d_in[3];
    const float* out_b = (const float*)d_in[4];
    float* out = (float*)d_out;

    const size_t NX  = (size_t)NTOK * EE;
    const size_t NW1 = (size_t)E3 * EE;
    const size_t NW2 = (size_t)EE * EE;
    const size_t NQ  = (size_t)NTOK * E3;

    u16* ws   = (u16*)d_ws;
    u16* x_h  = ws;                 // reused as attn O (f16) after gemm1 consumes x
    u16* w1h  = ws + NX;
    u16* w2h  = w1h + NW1;
    u16* qkvb = w2h + NW2;
    u16* vtb  = qkvb + NQ;

    split3<<<dim3((unsigned)((NX + NW1 + NW2) / 4 / 256)), 256, 0, stream>>>(
        x, qkv_w, out_w, x_h, w1h, w2h);

    gemm_f16<4, true, true><<<dim3(E3 / 128, NTOK / 128), 256, 0, stream>>>(
        x_h, w1h, qkv_b, (void*)qkvb, NTOK, E3);

    vtrans<<<dim3(TT / 64, HH, BB), 256, 0, stream>>>(qkvb, vtb);

    attn_mfma<<<dim3(TT / 64, HH, BB), 256, 0, stream>>>(qkvb, vtb, x_h);

    gemm_f16<2, false, false><<<dim3(EE / 128, NTOK / 64), 256, 0, stream>>>(
        x_h, w2h, out_b, (void*)out, NTOK, EE);
}

// Round 2
// 188.204 us; speedup vs baseline: 1.0262x; 1.0121x over previous
//
#include <hip/hip_runtime.h>

#define TT 2048
#define BB 2
#define EE 1024
#define HH 16
#define DD 64
#define E3 3072
#define NTOK 4096

typedef unsigned short u16;
typedef _Float16 __attribute__((ext_vector_type(8))) half8;
typedef _Float16 __attribute__((ext_vector_type(4))) half4;
typedef __fp16 __attribute__((ext_vector_type(2))) fp16x2;
typedef __attribute__((ext_vector_type(4))) float f32x4;

__device__ __forceinline__ unsigned f2h(float f) {
    union { _Float16 h; u16 u; } v; v.h = (_Float16)f; return (unsigned)v.u;
}
// packed f32x2 -> f16x2 (round-toward-zero), one VALU op
__device__ __forceinline__ fp16x2 pk2(float a, float b) {
    return __builtin_amdgcn_cvt_pkrtz(a, b);
}

// async global->LDS, 16 B per lane; lds ptr must be wave-uniform
__device__ __forceinline__ void async_ld16(const u16* g, const u16* l) {
    auto gp = reinterpret_cast<const __attribute__((address_space(1))) unsigned*>(
        reinterpret_cast<uintptr_t>(g));
    auto lp = reinterpret_cast<__attribute__((address_space(3))) unsigned*>(
        reinterpret_cast<uintptr_t>(l));
    __builtin_amdgcn_global_load_lds(gp, lp, 16, 0, 0);
}

// fp32 -> f16 convert for x, qkv_w, out_w in ONE launch.
__global__ __launch_bounds__(256) void split3(
    const float* __restrict__ x, const float* __restrict__ w1,
    const float* __restrict__ w2,
    u16* __restrict__ xh, u16* __restrict__ w1h, u16* __restrict__ w2h)
{
    const int N1 = (NTOK * EE) / 4;
    const int N2 = N1 + (E3 * EE) / 4;
    int i = blockIdx.x * 256 + threadIdx.x;
    const float* src; u16* dst; int j;
    if (i < N1)      { src = x;  dst = xh;  j = i; }
    else if (i < N2) { src = w1; dst = w1h; j = i - N1; }
    else             { src = w2; dst = w2h; j = i - N2; }
    float4 v = ((const float4*)src)[j];
    *(uint2*)&dst[(size_t)j * 4] = make_uint2(
        f2h(v.x) | (f2h(v.y) << 16), f2h(v.z) | (f2h(v.w) << 16));
}

// One-shot V transpose: qkv[b][t][2E + h*64 + d] -> vt[b][h][d][t]  (f16 bits)
__global__ __launch_bounds__(256) void vtrans(
    const u16* __restrict__ qkv, u16* __restrict__ vt)
{
    __shared__ u16 L[64][72];
    const int tid = threadIdx.x;
    const int t0 = blockIdx.x * 64;
    const int h  = blockIdx.y;
    const int b  = blockIdx.z;
    const int row = tid >> 2;
    const int c16 = (tid & 3) << 4;

    const u16* src = qkv + (size_t)(b * TT + t0 + row) * E3 + 2 * EE + h * DD + c16;
    *(uint4*)&L[row][c16]     = *(const uint4*)src;
    *(uint4*)&L[row][c16 + 8] = *(const uint4*)(src + 8);
    __syncthreads();

    union { uint4 u[2]; u16 s[16]; } P;
#pragma unroll
    for (int j = 0; j < 16; ++j) P.s[j] = L[c16 + j][row];
    u16* dst = vt + ((size_t)(b * HH + h) * DD + row) * TT + t0 + c16;
    *(uint4*)dst       = P.u[0];
    *(uint4*)(dst + 8) = P.u[1];
}

// f16 MFMA GEMM, BK=64 (half the barriers of BK=32):
// C[M,N] = A[M,1024] @ W[N,1024]^T + bias.  QSCALE: q-third (n0<EE) of the
// output is multiplied by 0.125*log2(e) so attention can use exp2 directly.
template <int WMT, bool QSCALE, bool F16OUT>
__global__ __launch_bounds__(256, 3) void gemm_f16(
    const u16* __restrict__ Ag, const u16* __restrict__ Wg,
    const float* __restrict__ bias, void* __restrict__ Cout, int M, int N)
{
    constexpr int BM = WMT * 32;
    constexpr int APASS = BM / 32;
    __shared__ u16 sA[BM * 64];
    __shared__ u16 sB[128 * 64];

    const int tid  = threadIdx.x;
    const int lane = tid & 63;
    const int wave = tid >> 6;
    const int quad = lane >> 4;
    const int l16  = lane & 15;
    const int wm = wave >> 1, wn = wave & 1;
    const int m0 = blockIdx.y * BM;
    const int n0 = blockIdx.x * 128;

    const int srow = tid >> 3;      // staging row (+32/pass)
    const int schk = tid & 7;       // 16B chunk

    const u16* ag[APASS]; int aldw[APASS];
#pragma unroll
    for (int p = 0; p < APASS; ++p) {
        int row = p * 32 + srow;
        ag[p] = Ag + (size_t)(m0 + row) * EE + ((schk ^ (row & 7)) << 3);
        aldw[p] = (p * 256 + wave * 64) * 8;
    }
    const u16* bg[4]; int bldw[4];
#pragma unroll
    for (int p = 0; p < 4; ++p) {
        int row = p * 32 + srow;
        bg[p] = Wg + (size_t)(n0 + row) * EE + ((schk ^ (row & 7)) << 3);
        bldw[p] = (p * 256 + wave * 64) * 8;
    }

    f32x4 acc[WMT][4];
#pragma unroll
    for (int mt = 0; mt < WMT; ++mt)
#pragma unroll
        for (int nt = 0; nt < 4; ++nt) acc[mt][nt] = (f32x4){0.f, 0.f, 0.f, 0.f};

    for (int k0 = 0; k0 < EE; k0 += 64) {
        __syncthreads();
#pragma unroll
        for (int p = 0; p < APASS; ++p) async_ld16(ag[p] + k0, sA + aldw[p]);
#pragma unroll
        for (int p = 0; p < 4; ++p)    async_ld16(bg[p] + k0, sB + bldw[p]);
        __syncthreads();

        half8 fa[WMT][2], fb[4][2];
#pragma unroll
        for (int mt = 0; mt < WMT; ++mt) {
            int r = wm * (WMT * 16) + mt * 16 + l16;
#pragma unroll
            for (int ks = 0; ks < 2; ++ks)
                fa[mt][ks] = *(const half8*)&sA[r * 64 + (((ks * 4 + quad) ^ (r & 7)) << 3)];
        }
#pragma unroll
        for (int nt = 0; nt < 4; ++nt) {
            int r = wn * 64 + nt * 16 + l16;
#pragma unroll
            for (int ks = 0; ks < 2; ++ks)
                fb[nt][ks] = *(const half8*)&sB[r * 64 + (((ks * 4 + quad) ^ (r & 7)) << 3)];
        }
#pragma unroll
        for (int ks = 0; ks < 2; ++ks)
#pragma unroll
            for (int mt = 0; mt < WMT; ++mt)
#pragma unroll
                for (int nt = 0; nt < 4; ++nt)
                    acc[mt][nt] = __builtin_amdgcn_mfma_f32_16x16x32_f16(
                        fa[mt][ks], fb[nt][ks], acc[mt][nt], 0, 0, 0);
    }

    const float scale = (QSCALE && n0 < EE) ? 0.18033688011112042f : 1.0f;
    float bv[4];
#pragma unroll
    for (int nt = 0; nt < 4; ++nt) bv[nt] = bias[n0 + wn * 64 + nt * 16 + l16];
#pragma unroll
    for (int mt = 0; mt < WMT; ++mt)
#pragma unroll
        for (int nt = 0; nt < 4; ++nt)
#pragma unroll
            for (int r = 0; r < 4; ++r) {
                int rg = m0 + wm * (WMT * 16) + mt * 16 + quad * 4 + r;
                int cg = n0 + wn * 64 + nt * 16 + l16;
                float v = (acc[mt][nt][r] + bv[nt]) * scale;
                if (F16OUT) ((u16*)Cout)[(size_t)rg * N + cg] = (u16)f2h(v);
                else        ((float*)Cout)[(size_t)rg * N + cg] = v;
            }
}

// S^T/O^T f16 MFMA flash attention, 32 q/wave, 2-wave blocks (64 q/block).
// LDS-BW diet (prev round proved LDS-bound, ~24 KB LDS traffic per wave-iter
// for 16 MFMAs): the P matrix never touches LDS. Per 16-key group the S^T
// MFMA C-layout (col=q=l16, row=key=quad*4+r) IS the B-operand layout of
// v_mfma_f32_16x16x16_f16 (col=l16, k=quad*4..+4), so exp2+cvt_pkrtz in
// registers feeds PV directly. Q frags load straight from global (QP buffer
// gone). LDS: KB+VB dbuf = 32 KB -> 4 blocks/CU, grid 1024.
// Per-wave-iter LDS: 8 b128 K + 16 b64 V = 16 KB for 32 q (was 24 KB for 16).
__global__ __launch_bounds__(128, 2) void attn_mfma(
    const u16* __restrict__ qkv, const u16* __restrict__ vt,
    u16* __restrict__ obuf)
{
    __shared__ u16 KB[2][64][64];   // [buf][key][d chunks swz]
    __shared__ u16 VB[2][64][64];   // [buf][d][key chunks swz]

    const int tid  = threadIdx.x;
    const int wave = tid >> 6;
    const int lane = tid & 63;
    const int quad = lane >> 4;
    const int l16  = lane & 15;

    const int q0 = blockIdx.x * 64;
    const int hh = blockIdx.y;
    const int b  = blockIdx.z;

    const int srow = tid >> 3;      // 0..15 (16 rows per pass, 2 waves)
    const int schk = tid & 7;
    const int ldsw = wave * 512;    // u16 elements: per-wave 1 KB chunk

    // ---- Q fragments straight from global (once, 4 x 16B per lane) ----
    half8 qb[2][2];
#pragma unroll
    for (int qt = 0; qt < 2; ++qt) {
        int row = q0 + wave * 32 + qt * 16 + l16;
        const u16* qg = qkv + (size_t)(b * TT + row) * E3 + hh * DD;
#pragma unroll
        for (int ks = 0; ks < 2; ++ks)
            qb[qt][ks] = *(const half8*)(qg + ks * 32 + quad * 8);
    }

    // ---- stage K/V tile 0 (4 passes x 16 rows) ----
#pragma unroll
    for (int p = 0; p < 4; ++p) {
        int row = p * 16 + srow;
        int sw8 = (schk ^ (row & 7)) << 3;
        async_ld16(qkv + (size_t)(b * TT + row) * E3 + EE + hh * DD + sw8,
                   &KB[0][0][0] + p * 1024 + ldsw);
        async_ld16(vt + ((size_t)(b * HH + hh) * DD + row) * TT + sw8,
                   &VB[0][0][0] + p * 1024 + ldsw);
    }
    __syncthreads();

    const f32x4 Z = {0.f, 0.f, 0.f, 0.f};
    float l_i[2] = {0.f, 0.f};
    f32x4 o[4][2];                  // [dt][qt]
#pragma unroll
    for (int dt = 0; dt < 4; ++dt)
#pragma unroll
        for (int qt = 0; qt < 2; ++qt) o[dt][qt] = (f32x4){0.f, 0.f, 0.f, 0.f};

    int cur = 0;
    for (int kt = 0; kt < TT; kt += 64, cur ^= 1) {
        // ---- prefetch next K/V tile into alternate buffer ----
        const int ktn = (kt + 64) & (TT - 1);
#pragma unroll
        for (int p = 0; p < 4; ++p) {
            int row = p * 16 + srow;
            int sw8 = (schk ^ (row & 7)) << 3;
            async_ld16(qkv + (size_t)(b * TT + ktn + row) * E3 + EE + hh * DD + sw8,
                       &KB[cur ^ 1][0][0] + p * 1024 + ldsw);
            async_ld16(vt + ((size_t)(b * HH + hh) * DD + row) * TT + ktn + sw8,
                       &VB[cur ^ 1][0][0] + p * 1024 + ldsw);
        }

        // ---- per 16-key group: S^T -> exp2 in-reg -> PV (no LDS P) ----
#pragma unroll
        for (int kg = 0; kg < 4; ++kg) {
            int r0 = kg * 16 + l16;
            half8 kf0 = *(const half8*)&KB[cur][r0][((quad)     ^ (r0 & 7)) << 3];
            half8 kf1 = *(const half8*)&KB[cur][r0][((4 + quad) ^ (r0 & 7)) << 3];

            half4 pb[2];
#pragma unroll
            for (int qt = 0; qt < 2; ++qt) {
                f32x4 t = __builtin_amdgcn_mfma_f32_16x16x32_f16(kf0, qb[qt][0], Z, 0, 0, 0);
                f32x4 s = __builtin_amdgcn_mfma_f32_16x16x32_f16(kf1, qb[qt][1], t, 0, 0, 0);
                float p0 = __builtin_amdgcn_exp2f(s[0]);
                float p1 = __builtin_amdgcn_exp2f(s[1]);
                float p2 = __builtin_amdgcn_exp2f(s[2]);
                float p3 = __builtin_amdgcn_exp2f(s[3]);
                l_i[qt] += (p0 + p1) + (p2 + p3);
                union { fp16x2 h[2]; half4 v; } u;
                u.h[0] = pk2(p0, p1);
                u.h[1] = pk2(p2, p3);
                pb[qt] = u.v;       // B-frag of 16x16x16: k = quad*4+r, col = l16
            }
#pragma unroll
            for (int dt = 0; dt < 4; ++dt) {
                int vr = dt * 16 + l16;
                int chunk = (kg * 2 + (quad >> 1)) ^ (vr & 7);
                half4 vf = *(const half4*)&VB[cur][vr][chunk * 8 + ((quad & 1) << 2)];
                o[dt][0] = __builtin_amdgcn_mfma_f32_16x16x16f16(vf, pb[0], o[dt][0], 0, 0, 0);
                o[dt][1] = __builtin_amdgcn_mfma_f32_16x16x16f16(vf, pb[1], o[dt][1], 0, 0, 0);
            }
        }

        __syncthreads();   // publishes prefetch + closes buffer swap
    }

    // ---- epilogue: reduce l over quad-groups, normalize, store f16 ----
    float inv[2];
#pragma unroll
    for (int qt = 0; qt < 2; ++qt) {
        float l = l_i[qt];
        l += __shfl_xor(l, 16, 64);
        l += __shfl_xor(l, 32, 64);
        inv[qt] = 1.f / l;
    }
#pragma unroll
    for (int qt = 0; qt < 2; ++qt) {
        size_t base = (size_t)(b * TT + q0 + wave * 32 + qt * 16 + l16) * EE + hh * DD;
#pragma unroll
        for (int dt = 0; dt < 4; ++dt) {
            unsigned hv[4];
#pragma unroll
            for (int r = 0; r < 4; ++r) hv[r] = f2h(o[dt][qt][r] * inv[qt]);
            *(uint2*)&obuf[base + dt * 16 + quad * 4] =
                make_uint2(hv[0] | (hv[1] << 16), hv[2] | (hv[3] << 16));
        }
    }
}

extern "C" void kernel_launch(void* const* d_in, const int* in_sizes, int n_in,
                              void* d_out, int out_size, void* d_ws, size_t ws_size,
                              hipStream_t stream)
{
    const float* x     = (const float*)d_in[0];
    const float* qkv_w = (const float*)d_in[1];
    const float* qkv_b = (const float*)d_in[2];
    const float* out_w = (const float*)d_in[3];
    const float* out_b = (const float*)d_in[4];
    float* out = (float*)d_out;

    const size_t NX  = (size_t)NTOK * EE;
    const size_t NW1 = (size_t)E3 * EE;
    const size_t NW2 = (size_t)EE * EE;
    const size_t NQ  = (size_t)NTOK * E3;

    u16* ws   = (u16*)d_ws;
    u16* x_h  = ws;                 // reused as attn O (f16) after gemm1 consumes x
    u16* w1h  = ws + NX;
    u16* w2h  = w1h + NW1;
    u16* qkvb = w2h + NW2;
    u16* vtb  = qkvb + NQ;

    split3<<<dim3((unsigned)((NX + NW1 + NW2) / 4 / 256)), 256, 0, stream>>>(
        x, qkv_w, out_w, x_h, w1h, w2h);

    gemm_f16<4, true, true><<<dim3(E3 / 128, NTOK / 128), 256, 0, stream>>>(
        x_h, w1h, qkv_b, (void*)qkvb, NTOK, E3);

    vtrans<<<dim3(TT / 64, HH, BB), 256, 0, stream>>>(qkvb, vtb);

    attn_mfma<<<dim3(TT / 64, HH, BB), 128, 0, stream>>>(qkvb, vtb, x_h);

    gemm_f16<2, false, false><<<dim3(EE / 128, NTOK / 64), 256, 0, stream>>>(
        x_h, w2h, out_b, (void*)out, NTOK, EE);
}